// Round 1
// baseline (27344.336 us; speedup 1.0000x reference)
//
#include <hip/hip_runtime.h>
#include <stdint.h>
#include <stddef.h>

typedef __bf16 bf16;
typedef __bf16 bf16x8 __attribute__((ext_vector_type(8)));
typedef __bf16 bf16x4 __attribute__((ext_vector_type(4)));
typedef float  f32x4  __attribute__((ext_vector_type(4)));

#define B_ 8
#define T_ 2048
#define D_ 1024
#define L_ 2

#define AS1C(p) ((const __attribute__((address_space(1))) void*)(p))
#define AS3(p)  ((__attribute__((address_space(3))) void*)(p))

// ---------------- f32 -> bf16 convert (weights) ----------------
__global__ __launch_bounds__(256) void cvt_kernel(const float* __restrict__ in,
                                                  bf16* __restrict__ out, int n4) {
  int i = blockIdx.x * 256 + threadIdx.x;
  if (i >= n4) return;
  float4 v = ((const float4*)in)[i];
  bf16x4 o = { (bf16)v.x, (bf16)v.y, (bf16)v.z, (bf16)v.w };
  ((bf16x4*)out)[i] = o;
}

// ---------------- LayerNorm: one 256-thr block per row, D=1024 ----------------
__global__ __launch_bounds__(256) void ln_kernel(const float* __restrict__ x,
                                                 const float* __restrict__ g,
                                                 const float* __restrict__ b,
                                                 bf16* __restrict__ xn) {
  const int row = blockIdx.x;
  const int tid = threadIdx.x;
  const float4 v = ((const float4*)(x + (size_t)row * D_))[tid];
  float s1 = v.x + v.y + v.z + v.w;
  float s2 = v.x * v.x + v.y * v.y + v.z * v.z + v.w * v.w;
#pragma unroll
  for (int off = 1; off < 64; off <<= 1) {
    s1 += __shfl_xor(s1, off);
    s2 += __shfl_xor(s2, off);
  }
  __shared__ float r1[4], r2[4];
  if ((tid & 63) == 0) { r1[tid >> 6] = s1; r2[tid >> 6] = s2; }
  __syncthreads();
  s1 = r1[0] + r1[1] + r1[2] + r1[3];
  s2 = r2[0] + r2[1] + r2[2] + r2[3];
  const float mu = s1 * (1.f / D_);
  const float var = s2 * (1.f / D_) - mu * mu;
  const float rs = rsqrtf(var + 1e-5f);
  const float4 gv = ((const float4*)g)[tid];
  const float4 bv = ((const float4*)b)[tid];
  bf16x4 o = { (bf16)((v.x - mu) * rs * gv.x + bv.x),
               (bf16)((v.y - mu) * rs * gv.y + bv.y),
               (bf16)((v.z - mu) * rs * gv.z + bv.z),
               (bf16)((v.w - mu) * rs * gv.w + bv.w) };
  ((bf16x4*)(xn + (size_t)row * D_))[tid] = o;
}

// ---------------- bf16 MFMA GEMM, C[m,n] = sum_k A[m,k]*Bw[n,k] (+bias +resid) --
// 128x128 tile, BK=32, 4 waves (2x2), m97-style global_load_lds staging.
__global__ __launch_bounds__(256) void gemm_bt(const bf16* __restrict__ A,
                                               const bf16* __restrict__ Bw,
                                               const float* __restrict__ bias,
                                               const float* __restrict__ resid,
                                               float* __restrict__ C,
                                               int M, int N, int K) {
  __shared__ bf16 As[128 * 32];
  __shared__ bf16 Bs[128 * 32];
  const int tid = threadIdx.x;
  const int lane = tid & 63;
  const int wave = tid >> 6;
  const int m0 = blockIdx.y * 128;
  const int n0 = blockIdx.x * 128;
  const int wm = (wave >> 1) * 64;
  const int wn = (wave & 1) * 64;
  f32x4 acc[4][4] = {};

  for (int kt = 0; kt < K; kt += 32) {
#pragma unroll
    for (int it = 0; it < 2; ++it) {
      const int gidx = it * 256 + tid;      // granule 0..511 (16B each)
      const int row = gidx >> 2;            // tile row 0..127
      const int col = (gidx & 3) << 3;      // k offset 0/8/16/24
      __builtin_amdgcn_global_load_lds(AS1C(A + (size_t)(m0 + row) * K + kt + col),
                                       AS3(&As[gidx * 8]), 16, 0, 0);
      __builtin_amdgcn_global_load_lds(AS1C(Bw + (size_t)(n0 + row) * K + kt + col),
                                       AS3(&Bs[gidx * 8]), 16, 0, 0);
    }
    __syncthreads();
    bf16x8 af[4], bfr[4];
#pragma unroll
    for (int i = 0; i < 4; ++i)
      af[i] = *(const bf16x8*)&As[(wm + i * 16 + (lane & 15)) * 32 + (lane >> 4) * 8];
#pragma unroll
    for (int j = 0; j < 4; ++j)
      bfr[j] = *(const bf16x8*)&Bs[(wn + j * 16 + (lane & 15)) * 32 + (lane >> 4) * 8];
#pragma unroll
    for (int i = 0; i < 4; ++i)
#pragma unroll
      for (int j = 0; j < 4; ++j)
        acc[i][j] = __builtin_amdgcn_mfma_f32_16x16x32_bf16(af[i], bfr[j], acc[i][j], 0, 0, 0);
    __syncthreads();
  }

  const int cr = (lane >> 4) * 4;  // C row base within 16x16 frag (m89 layout)
  const int cc = lane & 15;        // C col within frag
#pragma unroll
  for (int i = 0; i < 4; ++i) {
#pragma unroll
    for (int j = 0; j < 4; ++j) {
      const int mb = m0 + wm + i * 16 + cr;
      const int n = n0 + wn + j * 16 + cc;
      const float bn = bias ? bias[n] : 0.f;
#pragma unroll
      for (int r = 0; r < 4; ++r) {
        const size_t idx = (size_t)(mb + r) * N + n;
        float vv = acc[i][j][r] + bn;
        if (resid) vv += resid[idx];
        C[idx] = vv;
      }
    }
  }
}

// ---------------- sequential scan: 8 batch groups x 16 WGs, W_h slice in LDS ----
__global__ __launch_bounds__(256) void scan_kernel(const float* __restrict__ uv,
                                                   const bf16* __restrict__ Wh,
                                                   const float* __restrict__ bh,
                                                   float* __restrict__ h0buf,
                                                   float* __restrict__ h1buf,
                                                   bf16* __restrict__ Hout,
                                                   unsigned* __restrict__ bar) {
  const int tid = threadIdx.x;
  const int b = blockIdx.x >> 4;
  const int s = blockIdx.x & 15;
  const int j0 = s << 6;  // 64 output cols per WG

  __shared__ bf16 Wt[1024][64];  // transposed slice [k][j], 128 KiB
  __shared__ float hs[1024];
  __shared__ float red[8][64];

  // load + transpose W slice (coalesced global reads along k)
  for (int idx = tid; idx < 64 * 1024; idx += 256) {
    const int j = idx >> 10;
    const int k = idx & 1023;
    Wt[k][j] = Wh[(size_t)(j0 + j) * 1024 + k];
  }
  float bhreg = 0.f;
  if (tid < 64) bhreg = bh[j0 + tid];

  const int jj = tid & 31;   // j-pair index: cols 2jj, 2jj+1
  const int p = tid >> 5;    // k chunk 0..7 (128 each)
  const int kbase = p << 7;

  float* hcur = h0buf + b * 1024;
  float* hnxt = h1buf + b * 1024;
  unsigned* const barb = bar + b * 16;  // 64B-padded counters
  __syncthreads();

  for (int t = 0; t < T_; ++t) {
    float u_t = 0.f, v_t = 0.f;
    if (tid < 64) {  // wave 0 only: issue u/v loads early
      const size_t rowi = (size_t)(b * T_ + t) * (2 * D_);
      u_t = uv[rowi + j0 + tid];
      v_t = uv[rowi + D_ + j0 + tid];
    }
    ((float4*)hs)[tid] = ((const float4*)hcur)[tid];  // stage h into LDS
    __syncthreads();

    float2 pacc = {0.f, 0.f};
#pragma unroll 8
    for (int i = 0; i < 128; ++i) {
      const float hk = hs[kbase + i];
      const unsigned wp = *(const unsigned*)&Wt[kbase + i][jj << 1];
      pacc.x = fmaf(__uint_as_float(wp << 16), hk, pacc.x);
      pacc.y = fmaf(__uint_as_float(wp & 0xffff0000u), hk, pacc.y);
    }
    *(float2*)&red[p][jj << 1] = pacc;
    __syncthreads();

    if (tid < 64) {
      float dot = red[0][tid];
#pragma unroll
      for (int q = 1; q < 8; ++q) dot += red[q][tid];
      const float gate = 1.f / (1.f + __expf(-u_t));
      const float cand = tanhf(v_t + dot + bhreg);
      const float hp = hs[j0 + tid];
      const float hn = fmaf(gate, cand - hp, hp);
      hnxt[j0 + tid] = hn;
      Hout[(size_t)(b * T_ + t) * D_ + j0 + tid] = (bf16)hn;
    }
    __syncthreads();  // all lanes' writes done before the release
    if (tid == 0) {
      __threadfence();
      __hip_atomic_fetch_add(barb, 1u, __ATOMIC_RELEASE, __HIP_MEMORY_SCOPE_AGENT);
      const unsigned target = 16u * (unsigned)(t + 1);
      while (__hip_atomic_load(barb, __ATOMIC_RELAXED, __HIP_MEMORY_SCOPE_AGENT) < target)
        __builtin_amdgcn_s_sleep(2);
      (void)__hip_atomic_load(barb, __ATOMIC_ACQUIRE, __HIP_MEMORY_SCOPE_AGENT);
    }
    __syncthreads();
    float* tmp = hcur; hcur = hnxt; hnxt = tmp;  // ping-pong
  }
}

extern "C" void kernel_launch(void* const* d_in, const int* in_sizes, int n_in,
                              void* d_out, int out_size, void* d_ws, size_t ws_size,
                              hipStream_t stream) {
  const float* x     = (const float*)d_in[0];
  const float* ln_g  = (const float*)d_in[1];
  const float* ln_b  = (const float*)d_in[2];
  const float* W_in  = (const float*)d_in[3];
  const float* b_in  = (const float*)d_in[4];
  const float* W_h   = (const float*)d_in[5];
  const float* b_h   = (const float*)d_in[6];
  const float* W_out = (const float*)d_in[7];
  const float* b_out = (const float*)d_in[8];
  float* out = (float*)d_out;

  char* ws = (char*)d_ws;
  size_t off = 0;
  auto alloc = [&](size_t bytes) -> void* {
    void* p = ws + off;
    off = (off + bytes + 255) & ~(size_t)255;
    return p;
  };
  bf16* wInB  = (bf16*)alloc((size_t)L_ * 2 * D_ * D_ * 2);
  bf16* wHB   = (bf16*)alloc((size_t)L_ * D_ * D_ * 2);
  bf16* wOutB = (bf16*)alloc((size_t)L_ * D_ * D_ * 2);
  bf16* Xn    = (bf16*)alloc((size_t)B_ * T_ * D_ * 2);
  float* uvb  = (float*)alloc((size_t)B_ * T_ * 2 * D_ * 4);
  bf16* Hb    = (bf16*)alloc((size_t)B_ * T_ * D_ * 2);
  float* h0   = (float*)alloc(B_ * D_ * 4);
  float* h1   = (float*)alloc(B_ * D_ * 4);
  unsigned* bar = (unsigned*)alloc(8 * 16 * 4);
  (void)ws_size; (void)in_sizes; (void)n_in; (void)out_size;  // ~208 MB used

  // weights -> bf16 (every call; no cached state)
  {
    int n4 = L_ * 2 * D_ * D_ / 4;
    cvt_kernel<<<(n4 + 255) / 256, 256, 0, stream>>>(W_in, wInB, n4);
    n4 = L_ * D_ * D_ / 4;
    cvt_kernel<<<(n4 + 255) / 256, 256, 0, stream>>>(W_h, wHB, n4);
    cvt_kernel<<<(n4 + 255) / 256, 256, 0, stream>>>(W_out, wOutB, n4);
  }

  const int Mrows = B_ * T_;  // 16384
  for (int l = 0; l < L_; ++l) {
    const float* lin = (l == 0) ? x : out;
    ln_kernel<<<Mrows, 256, 0, stream>>>(lin, ln_g + l * D_, ln_b + l * D_, Xn);

    dim3 g1(2 * D_ / 128, Mrows / 128);
    gemm_bt<<<g1, 256, 0, stream>>>(Xn, wInB + (size_t)l * 2 * D_ * D_,
                                    b_in + l * 2 * D_, nullptr, uvb,
                                    Mrows, 2 * D_, D_);

    hipMemsetAsync(bar, 0, 8 * 16 * 4, stream);
    hipMemsetAsync(h0, 0, B_ * D_ * 4, stream);
    scan_kernel<<<128, 256, 0, stream>>>(uvb, wHB + (size_t)l * D_ * D_,
                                         b_h + l * D_, h0, h1, Hb, bar);

    dim3 g2(D_ / 128, Mrows / 128);
    gemm_bt<<<g2, 256, 0, stream>>>(Hb, wOutB + (size_t)l * D_ * D_,
                                    b_out + l * D_, lin, out,
                                    Mrows, D_, D_);
  }
}

// Round 3
// 19180.698 us; speedup vs baseline: 1.4256x; 1.4256x over previous
//
#include <hip/hip_runtime.h>
#include <stdint.h>
#include <stddef.h>

typedef __bf16 bf16;
typedef __bf16 bf16x8 __attribute__((ext_vector_type(8)));
typedef __bf16 bf16x4 __attribute__((ext_vector_type(4)));
typedef float  f32x4  __attribute__((ext_vector_type(4)));

#define B_ 8
#define T_ 2048
#define D_ 1024
#define L_ 2

#define AS1C(p) ((const __attribute__((address_space(1))) void*)(p))
#define AS3(p)  ((__attribute__((address_space(3))) void*)(p))

// Compact frame layout (h-state after step t), 16384 B per frame, no garbage:
//   byte(t, b, n) = t*16384 + (n>>5)*512 + (((n&31)>>3)*8 + b)*16 + (n&7)*2
// b in [0,8), n in [0,1024). Expanded to 32KB MFMA-A-fragment layout in LDS
// during staging (rows 8..15 of each 16-row fragment are finite dummies).

// ---------------- f32 -> bf16 convert (weights) ----------------
__global__ __launch_bounds__(256) void cvt_kernel(const float* __restrict__ in,
                                                  bf16* __restrict__ out, int n4) {
  int i = blockIdx.x * 256 + threadIdx.x;
  if (i >= n4) return;
  float4 v = ((const float4*)in)[i];
  bf16x4 o = { (bf16)v.x, (bf16)v.y, (bf16)v.z, (bf16)v.w };
  ((bf16x4*)out)[i] = o;
}

// ---------------- LayerNorm ----------------
__global__ __launch_bounds__(256) void ln_kernel(const float* __restrict__ x,
                                                 const float* __restrict__ g,
                                                 const float* __restrict__ b,
                                                 bf16* __restrict__ xn) {
  const int row = blockIdx.x;
  const int tid = threadIdx.x;
  const float4 v = ((const float4*)(x + (size_t)row * D_))[tid];
  float s1 = v.x + v.y + v.z + v.w;
  float s2 = v.x * v.x + v.y * v.y + v.z * v.z + v.w * v.w;
#pragma unroll
  for (int off = 1; off < 64; off <<= 1) {
    s1 += __shfl_xor(s1, off);
    s2 += __shfl_xor(s2, off);
  }
  __shared__ float r1[4], r2[4];
  if ((tid & 63) == 0) { r1[tid >> 6] = s1; r2[tid >> 6] = s2; }
  __syncthreads();
  s1 = r1[0] + r1[1] + r1[2] + r1[3];
  s2 = r2[0] + r2[1] + r2[2] + r2[3];
  const float mu = s1 * (1.f / D_);
  const float var = s2 * (1.f / D_) - mu * mu;
  const float rs = rsqrtf(var + 1e-5f);
  const float4 gv = ((const float4*)g)[tid];
  const float4 bv = ((const float4*)b)[tid];
  bf16x4 o = { (bf16)((v.x - mu) * rs * gv.x + bv.x),
               (bf16)((v.y - mu) * rs * gv.y + bv.y),
               (bf16)((v.z - mu) * rs * gv.z + bv.z),
               (bf16)((v.w - mu) * rs * gv.w + bv.w) };
  ((bf16x4*)(xn + (size_t)row * D_))[tid] = o;
}

// ---------------- bf16 MFMA GEMM, C[m,n] = sum_k A[m,k]*Bw[n,k] (+bias +resid) --
__global__ __launch_bounds__(256) void gemm_bt(const bf16* __restrict__ A,
                                               const bf16* __restrict__ Bw,
                                               const float* __restrict__ bias,
                                               const float* __restrict__ resid,
                                               float* __restrict__ C,
                                               int M, int N, int K) {
  __shared__ bf16 As[128 * 32];
  __shared__ bf16 Bs[128 * 32];
  const int tid = threadIdx.x;
  const int lane = tid & 63;
  const int wave = tid >> 6;
  const int m0 = blockIdx.y * 128;
  const int n0 = blockIdx.x * 128;
  const int wm = (wave >> 1) * 64;
  const int wn = (wave & 1) * 64;
  f32x4 acc[4][4] = {};

  for (int kt = 0; kt < K; kt += 32) {
#pragma unroll
    for (int it = 0; it < 2; ++it) {
      const int gidx = it * 256 + tid;
      const int row = gidx >> 2;
      const int col = (gidx & 3) << 3;
      __builtin_amdgcn_global_load_lds(AS1C(A + (size_t)(m0 + row) * K + kt + col),
                                       AS3(&As[gidx * 8]), 16, 0, 0);
      __builtin_amdgcn_global_load_lds(AS1C(Bw + (size_t)(n0 + row) * K + kt + col),
                                       AS3(&Bs[gidx * 8]), 16, 0, 0);
    }
    __syncthreads();
    bf16x8 af[4], bfr[4];
#pragma unroll
    for (int i = 0; i < 4; ++i)
      af[i] = *(const bf16x8*)&As[(wm + i * 16 + (lane & 15)) * 32 + (lane >> 4) * 8];
#pragma unroll
    for (int j = 0; j < 4; ++j)
      bfr[j] = *(const bf16x8*)&Bs[(wn + j * 16 + (lane & 15)) * 32 + (lane >> 4) * 8];
#pragma unroll
    for (int i = 0; i < 4; ++i)
#pragma unroll
      for (int j = 0; j < 4; ++j)
        acc[i][j] = __builtin_amdgcn_mfma_f32_16x16x32_bf16(af[i], bfr[j], acc[i][j], 0, 0, 0);
    __syncthreads();
  }

  const int cr = (lane >> 4) * 4;
  const int cc = lane & 15;
#pragma unroll
  for (int i = 0; i < 4; ++i) {
#pragma unroll
    for (int j = 0; j < 4; ++j) {
      const int mb = m0 + wm + i * 16 + cr;
      const int n = n0 + wn + j * 16 + cc;
      const float bn = bias ? bias[n] : 0.f;
#pragma unroll
      for (int r = 0; r < 4; ++r) {
        const size_t idx = (size_t)(mb + r) * N + n;
        float vv = acc[i][j][r] + bn;
        if (resid) vv += resid[idx];
        C[idx] = vv;
      }
    }
  }
}

// ---- same GEMM but A comes from the compact frame-layout h buffer ----
__global__ __launch_bounds__(256) void gemm_hfrag(const char* __restrict__ Hb,
                                                  const bf16* __restrict__ Bw,
                                                  const float* __restrict__ bias,
                                                  const float* __restrict__ resid,
                                                  float* __restrict__ C,
                                                  int M, int N, int K) {
  __shared__ bf16 As[128 * 32];
  __shared__ bf16 Bs[128 * 32];
  const int tid = threadIdx.x;
  const int lane = tid & 63;
  const int wave = tid >> 6;
  const int m0 = blockIdx.y * 128;
  const int n0 = blockIdx.x * 128;
  const int wm = (wave >> 1) * 64;
  const int wn = (wave & 1) * 64;
  f32x4 acc[4][4] = {};

  for (int kt = 0; kt < K; kt += 32) {
#pragma unroll
    for (int it = 0; it < 2; ++it) {
      const int g = it * 256 + tid;        // granule: tile row r, k-sub
      const int r = g >> 2;
      const int sub = g & 3;
      const int R = m0 + r;
      const int bb = R >> 11;              // batch (T_=2048 rows each)
      const int tt = R & (T_ - 1);
      // A[bb][kt + sub*8 .. +8] in compact frame layout
      const char* src = Hb + (size_t)tt * 16384 + (size_t)(kt >> 5) * 512
                        + (sub * 8 + bb) * 16;
      __builtin_amdgcn_global_load_lds(AS1C(src), AS3(&As[g * 8]), 16, 0, 0);
      __builtin_amdgcn_global_load_lds(AS1C(Bw + (size_t)(n0 + r) * K + kt + (sub << 3)),
                                       AS3(&Bs[g * 8]), 16, 0, 0);
    }
    __syncthreads();
    bf16x8 af[4], bfr[4];
#pragma unroll
    for (int i = 0; i < 4; ++i)
      af[i] = *(const bf16x8*)&As[(wm + i * 16 + (lane & 15)) * 32 + (lane >> 4) * 8];
#pragma unroll
    for (int j = 0; j < 4; ++j)
      bfr[j] = *(const bf16x8*)&Bs[(wn + j * 16 + (lane & 15)) * 32 + (lane >> 4) * 8];
#pragma unroll
    for (int i = 0; i < 4; ++i)
#pragma unroll
      for (int j = 0; j < 4; ++j)
        acc[i][j] = __builtin_amdgcn_mfma_f32_16x16x32_bf16(af[i], bfr[j], acc[i][j], 0, 0, 0);
    __syncthreads();
  }

  const int cr = (lane >> 4) * 4;
  const int cc = lane & 15;
#pragma unroll
  for (int i = 0; i < 4; ++i) {
#pragma unroll
    for (int j = 0; j < 4; ++j) {
      const int mb = m0 + wm + i * 16 + cr;
      const int n = n0 + wn + j * 16 + cc;
      const float bn = bias[n];
#pragma unroll
      for (int r = 0; r < 4; ++r) {
        const size_t idx = (size_t)(mb + r) * N + n;
        C[idx] = acc[i][j][r] + bn + resid[idx];
      }
    }
  }
}

// ---------------- scan: 8 WGs x 512 thr, W_h in VGPRs, MFMA recurrence --------
__global__ __launch_bounds__(512, 2) void scan_kernel(const float* __restrict__ uvb,
                                                      const bf16* __restrict__ Wh,
                                                      const float* __restrict__ bh,
                                                      char* __restrict__ Hb,
                                                      unsigned* __restrict__ cnt) {
  const int tid = threadIdx.x;
  const int lane = tid & 63;
  const int wv = tid >> 6;
  const int Wg = blockIdx.x * 8 + wv;      // global wave id 0..63
  const int n0 = Wg * 16;                  // 16 output cols per wave
  const int kkw = Wg >> 1;                 // this wave's frame k-chunk
  const int c = lane & 15;                 // local col

  __shared__ __align__(16) char hA[32768]; // expanded A-fragment frame

  // W_h B-fragments in registers: wB[kk] = W_h[n0+c][kk*32 + (lane>>4)*8 .. +8]
  bf16x8 wB[32];
#pragma unroll
  for (int kk = 0; kk < 32; ++kk)
    wB[kk] = *(const bf16x8*)(Wh + ((size_t)(n0 + c) << 10) + kk * 32 + ((lane >> 4) << 3));

  const float bh_n = bh[n0 + c];
  const int sub = 2 * (Wg & 1) + (c >> 3);         // k-subgroup of col n0+c
  const int b0 = (lane >> 4) * 4;                  // first batch (C-frag rows), lanes<32
  const int offbase = kkw * 512 + (sub * 8 + b0) * 16 + (c & 7) * 2;

  // staging granule precompute: LDS granule g = i*512 + tid
  int sgk[4], sgoff[4];
#pragma unroll
  for (int i = 0; i < 4; ++i) {
    const int g = i * 512 + tid;
    const int l16 = g & 63;
    sgk[i] = g >> 6;                                // chunk kk
    sgoff[i] = sgk[i] * 512 + ((l16 >> 4) * 8 + (l16 & 7)) * 16;  // row&7 dummy copy
  }

  float hs0 = 0.f, hs1 = 0.f, hs2 = 0.f, hs3 = 0.f;

  for (int t = 0; t < T_; ++t) {
    // ---- prefetch u,v for this step (hidden under the poll) ----
    float u0, u1, u2, u3, v0, v1, v2, v3;
    if (lane < 32) {
      const float* uvp = uvb + ((size_t)b0 * T_ + t) * 2048 + n0 + c;
      u0 = uvp[0];                          v0 = uvp[1024];
      u1 = uvp[(size_t)1 * T_ * 2048];      v1 = uvp[(size_t)1 * T_ * 2048 + 1024];
      u2 = uvp[(size_t)2 * T_ * 2048];      v2 = uvp[(size_t)2 * T_ * 2048 + 1024];
      u3 = uvp[(size_t)3 * T_ * 2048];      v3 = uvp[(size_t)3 * T_ * 2048 + 1024];
    }

    f32x4 asum = {0.f, 0.f, 0.f, 0.f};
    if (t > 0) {
      // ---- wait for all 64 waves to have published frame[t-1] ----
      if (lane == 0) {
        const unsigned tgt = 64u * (unsigned)t;
        while (__hip_atomic_load(cnt, __ATOMIC_RELAXED, __HIP_MEMORY_SCOPE_AGENT) < tgt)
          __builtin_amdgcn_s_sleep(1);
        (void)__hip_atomic_load(cnt, __ATOMIC_ACQUIRE, __HIP_MEMORY_SCOPE_AGENT);
      }
      __builtin_amdgcn_sched_barrier(0);
      // ---- stage frame[t-1], expanding compact(16KB) -> fragment(32KB) ----
      const char* srcF = Hb + (size_t)(t - 1) * 16384;
#pragma unroll
      for (int i = 0; i < 4; ++i)
        __builtin_amdgcn_global_load_lds(AS1C(srcF + sgoff[i]),
                                         AS3(hA + (i * 512 + tid) * 16), 16, 0, 0);
      __syncthreads();
      // ---- h @ W_h^T: 16 cols x 8 batches (frag rows 8..15 are dummies) ----
      f32x4 a0 = {0.f, 0.f, 0.f, 0.f}, a1 = {0.f, 0.f, 0.f, 0.f};
#pragma unroll
      for (int kk = 0; kk < 32; kk += 2) {
        bf16x8 f0 = *(const bf16x8*)(hA + kk * 1024 + lane * 16);
        bf16x8 f1 = *(const bf16x8*)(hA + (kk + 1) * 1024 + lane * 16);
        a0 = __builtin_amdgcn_mfma_f32_16x16x32_bf16(f0, wB[kk], a0, 0, 0, 0);
        a1 = __builtin_amdgcn_mfma_f32_16x16x32_bf16(f1, wB[kk + 1], a1, 0, 0, 0);
      }
      asum = a0 + a1;
      __syncthreads();  // MFMA reads done before anyone re-stages hA next step
    }

    // ---- gate/cand epilogue + publish h (lanes 0..31 hold batches 0..7) ----
    if (lane < 32) {
      char* frame = Hb + (size_t)t * 16384;
#pragma unroll
      for (int r = 0; r < 4; ++r) {
        const float uu = (r == 0) ? u0 : (r == 1) ? u1 : (r == 2) ? u2 : u3;
        const float vv = (r == 0) ? v0 : (r == 1) ? v1 : (r == 2) ? v2 : v3;
        float& hh = (r == 0) ? hs0 : (r == 1) ? hs1 : (r == 2) ? hs2 : hs3;
        const float s = asum[r] + bh_n + vv;
        const float g = __builtin_amdgcn_rcpf(1.f + __expf(-uu));
        const float e = __expf(2.f * s);
        const float cand = 1.f - 2.f * __builtin_amdgcn_rcpf(e + 1.f);
        hh = fmaf(g, cand - hh, hh);
        unsigned short hbits = __builtin_bit_cast(unsigned short, (bf16)hh);
        __hip_atomic_store((unsigned short*)(frame + offbase + r * 16), hbits,
                           __ATOMIC_RELAXED, __HIP_MEMORY_SCOPE_AGENT);
      }
    }
    // ---- publish: release-add orders this wave's stores ----
    if (lane == 0)
      __hip_atomic_fetch_add(cnt, 1u, __ATOMIC_RELEASE, __HIP_MEMORY_SCOPE_AGENT);
  }
}

extern "C" void kernel_launch(void* const* d_in, const int* in_sizes, int n_in,
                              void* d_out, int out_size, void* d_ws, size_t ws_size,
                              hipStream_t stream) {
  const float* x     = (const float*)d_in[0];
  const float* ln_g  = (const float*)d_in[1];
  const float* ln_b  = (const float*)d_in[2];
  const float* W_in  = (const float*)d_in[3];
  const float* b_in  = (const float*)d_in[4];
  const float* W_h   = (const float*)d_in[5];
  const float* b_h   = (const float*)d_in[6];
  const float* W_out = (const float*)d_in[7];
  const float* b_out = (const float*)d_in[8];
  float* out = (float*)d_out;

  char* ws = (char*)d_ws;
  size_t off = 0;
  auto alloc = [&](size_t bytes) -> void* {
    void* p = ws + off;
    off = (off + bytes + 255) & ~(size_t)255;
    return p;
  };
  bf16* wInB  = (bf16*)alloc((size_t)L_ * 2 * D_ * D_ * 2);
  bf16* wHB   = (bf16*)alloc((size_t)L_ * D_ * D_ * 2);
  bf16* wOutB = (bf16*)alloc((size_t)L_ * D_ * D_ * 2);
  bf16* Xn    = (bf16*)alloc((size_t)B_ * T_ * D_ * 2);
  float* uvb  = (float*)alloc((size_t)B_ * T_ * 2 * D_ * 4);
  char* Hb    = (char*)alloc((size_t)T_ * 16384);   // compact h frames (32 MB)
  unsigned* cnt = (unsigned*)alloc(256);
  (void)ws_size; (void)in_sizes; (void)n_in; (void)out_size;  // ~219 MB used

  {
    int n4 = L_ * 2 * D_ * D_ / 4;
    cvt_kernel<<<(n4 + 255) / 256, 256, 0, stream>>>(W_in, wInB, n4);
    n4 = L_ * D_ * D_ / 4;
    cvt_kernel<<<(n4 + 255) / 256, 256, 0, stream>>>(W_h, wHB, n4);
    cvt_kernel<<<(n4 + 255) / 256, 256, 0, stream>>>(W_out, wOutB, n4);
  }

  const int Mrows = B_ * T_;  // 16384
  for (int l = 0; l < L_; ++l) {
    const float* lin = (l == 0) ? x : out;
    ln_kernel<<<Mrows, 256, 0, stream>>>(lin, ln_g + l * D_, ln_b + l * D_, Xn);

    dim3 g1(2 * D_ / 128, Mrows / 128);
    gemm_bt<<<g1, 256, 0, stream>>>(Xn, wInB + (size_t)l * 2 * D_ * D_,
                                    b_in + l * 2 * D_, nullptr, uvb,
                                    Mrows, 2 * D_, D_);

    hipMemsetAsync(cnt, 0, 4, stream);
    scan_kernel<<<8, 512, 0, stream>>>(uvb, wHB + (size_t)l * D_ * D_,
                                       b_h + l * D_, Hb, cnt);

    dim3 g2(D_ / 128, Mrows / 128);
    gemm_hfrag<<<g2, 256, 0, stream>>>(Hb, wOutB + (size_t)l * D_ * D_,
                                       b_out + l * D_, lin, out,
                                       Mrows, D_, D_);
  }
}